// Round 1
// baseline (3173.413 us; speedup 1.0000x reference)
//
#include <hip/hip_runtime.h>
#include <hip/hip_bf16.h>
#include <stdint.h>

#define M_NODES 100000
#define KF 256
#define NF 256
#define NRELS 3
#define NEDGES 300000

typedef __attribute__((ext_vector_type(8))) short bf16x8;
typedef __attribute__((ext_vector_type(4))) float f32x4;

__device__ __forceinline__ unsigned short f32_to_bf16(float f) {
    union { float f; uint32_t u; } c; c.f = f;
    uint32_t u = c.u;
    uint32_t r = (u + 0x7FFFu + ((u >> 16) & 1u)) >> 16;
    return (unsigned short)r;
}

__device__ __forceinline__ float bf16_to_f32(unsigned short s) {
    union { uint32_t u; float f; } c; c.u = ((uint32_t)s) << 16;
    return c.f;
}

// ---------------------------------------------------------------------------
// GEMM: h[r] = bf16( x @ W[r] ), x fp32 [M,256], W fp32 [3,256,256] (k-major)
// 128x128 tile, BK=32, 4 waves (2x2), each wave 64x64 via 4x4 mfma 16x16x32.
// fp32->bf16 conversion fused into LDS staging. LDS row stride 40 bf16 (80B,
// 16B-aligned rows; frag reads land ~2-way on banks = free).
// ---------------------------------------------------------------------------
__global__ __launch_bounds__(256, 2)
void gemm_xw(const float* __restrict__ x, const float* __restrict__ w,
             unsigned short* __restrict__ h)
{
    const int bm = blockIdx.x, bn = blockIdx.y, r = blockIdx.z;
    const float* __restrict__ W = w + (size_t)r * KF * NF;
    unsigned short* __restrict__ H = h + (size_t)r * M_NODES * NF;

    __shared__ short As[128 * 40];   // As[m][k]
    __shared__ short Bs[128 * 40];   // Bs[n][k]  (transposed so frag reads are contiguous)

    const int t = threadIdx.x;
    const int lane = t & 63;
    const int wid = t >> 6;
    const int wr = wid >> 1, wc = wid & 1;
    const int l16 = lane & 15, lg = lane >> 4;

    f32x4 acc[4][4] = {};

    const int m0 = bm * 128;

    for (int kt = 0; kt < KF / 32; ++kt) {
        __syncthreads();  // protect previous iteration's fragment reads

        // ---- stage A: 128x32 fp32 -> bf16 (16 elems/thread = 4 x float4)
#pragma unroll
        for (int i = 0; i < 4; ++i) {
            int li = (i * 256 + t) * 4;       // flat elem 0..4095
            int row = li >> 5, col = li & 31;
            int gm = m0 + row;
            float4 v = make_float4(0.f, 0.f, 0.f, 0.f);
            if (gm < M_NODES)
                v = *(const float4*)(x + (size_t)gm * KF + kt * 32 + col);
            short4 b;
            b.x = (short)f32_to_bf16(v.x);
            b.y = (short)f32_to_bf16(v.y);
            b.z = (short)f32_to_bf16(v.z);
            b.w = (short)f32_to_bf16(v.w);
            *(short4*)&As[row * 40 + col] = b;
        }
        // ---- stage B transposed: Bs[n][k], 2 k's packed per b32 write
#pragma unroll
        for (int i = 0; i < 8; ++i) {
            int p = i * 256 + t;              // 0..2047
            int n = p & 127, kp = p >> 7;     // kp 0..15 -> k = 2*kp
            float v0 = W[(size_t)(kt * 32 + kp * 2 + 0) * NF + bn * 128 + n];
            float v1 = W[(size_t)(kt * 32 + kp * 2 + 1) * NF + bn * 128 + n];
            uint32_t pk = (uint32_t)f32_to_bf16(v0) | ((uint32_t)f32_to_bf16(v1) << 16);
            *(uint32_t*)&Bs[n * 40 + kp * 2] = pk;
        }
        __syncthreads();

        // ---- fragments + MFMA
        bf16x8 a[4], b[4];
#pragma unroll
        for (int i = 0; i < 4; ++i)
            a[i] = *(bf16x8*)&As[(wr * 64 + i * 16 + l16) * 40 + lg * 8];
#pragma unroll
        for (int j = 0; j < 4; ++j)
            b[j] = *(bf16x8*)&Bs[(wc * 64 + j * 16 + l16) * 40 + lg * 8];
#pragma unroll
        for (int i = 0; i < 4; ++i)
#pragma unroll
            for (int j = 0; j < 4; ++j)
                acc[i][j] = __builtin_amdgcn_mfma_f32_16x16x32_bf16(
                    a[i], b[j], acc[i][j], 0, 0, 0);
    }

    // ---- C write: D[(lg*4+q)][l16] per 16x16 fragment (verified layout)
#pragma unroll
    for (int i = 0; i < 4; ++i) {
        int row_base = m0 + wr * 64 + i * 16 + lg * 4;
#pragma unroll
        for (int q = 0; q < 4; ++q) {
            int row = row_base + q;
            if (row < M_NODES) {
#pragma unroll
                for (int j = 0; j < 4; ++j) {
                    int col = bn * 128 + wc * 64 + j * 16 + l16;
                    H[(size_t)row * NF + col] = f32_to_bf16(acc[i][j][q]);
                }
            }
        }
    }
}

// ---------------------------------------------------------------------------
// Edge aggregation: one wave per edge. out[dst] += h[r][src] (fp32 atomics).
// Each lane: 8B bf16x4 load + 4 atomicAdd.
// ---------------------------------------------------------------------------
__global__ __launch_bounds__(256)
void edge_agg(const unsigned short* __restrict__ h,
              const int* __restrict__ src, const int* __restrict__ dst,
              float* __restrict__ out)
{
    int gw = (blockIdx.x * 256 + threadIdx.x) >> 6;   // global wave = edge idx
    if (gw >= NRELS * NEDGES) return;
    int lane = threadIdx.x & 63;
    int r = gw / NEDGES;
    int s = src[gw];
    int d = dst[gw];
    const unsigned short* hrow = h + ((size_t)r * M_NODES + (size_t)s) * NF;
    float* orow = out + (size_t)d * NF;
    ushort4 v = *(const ushort4*)(hrow + lane * 4);
    atomicAdd(orow + lane * 4 + 0, bf16_to_f32(v.x));
    atomicAdd(orow + lane * 4 + 1, bf16_to_f32(v.y));
    atomicAdd(orow + lane * 4 + 2, bf16_to_f32(v.z));
    atomicAdd(orow + lane * 4 + 3, bf16_to_f32(v.w));
}

// ---------------------------------------------------------------------------
// In-place ReLU
// ---------------------------------------------------------------------------
__global__ __launch_bounds__(256)
void relu_k(float* __restrict__ out, int n4)
{
    int i = blockIdx.x * blockDim.x + threadIdx.x;
    int stride = gridDim.x * blockDim.x;
    for (; i < n4; i += stride) {
        float4 v = ((const float4*)out)[i];
        v.x = fmaxf(v.x, 0.f);
        v.y = fmaxf(v.y, 0.f);
        v.z = fmaxf(v.z, 0.f);
        v.w = fmaxf(v.w, 0.f);
        ((float4*)out)[i] = v;
    }
}

extern "C" void kernel_launch(void* const* d_in, const int* in_sizes, int n_in,
                              void* d_out, int out_size, void* d_ws, size_t ws_size,
                              hipStream_t stream)
{
    const float* x   = (const float*)d_in[0];
    const float* w   = (const float*)d_in[1];
    const int*   src = (const int*)d_in[2];
    const int*   dst = (const int*)d_in[3];
    float* out = (float*)d_out;
    unsigned short* h = (unsigned short*)d_ws;   // bf16 h[3][100000][256] = 153.6 MB

    hipMemsetAsync(d_out, 0, (size_t)M_NODES * NF * sizeof(float), stream);

    dim3 gg((M_NODES + 127) / 128, NF / 128, NRELS);
    gemm_xw<<<gg, 256, 0, stream>>>(x, w, h);

    int total_waves = NRELS * NEDGES;
    int blocks = (total_waves + 3) / 4;                 // 4 waves/block
    edge_agg<<<blocks, 256, 0, stream>>>(h, src, dst, out);

    relu_k<<<2048, 256, 0, stream>>>(out, M_NODES * NF / 4);
}

// Round 2
// 386.744 us; speedup vs baseline: 8.2055x; 8.2055x over previous
//
#include <hip/hip_runtime.h>
#include <hip/hip_bf16.h>
#include <stdint.h>

#define M_NODES 100000
#define KF 256
#define NF 256
#define NRELS 3
#define NEDGES 300000
#define TOT_EDGES (NRELS * NEDGES)
#define NB 391   // ceil(100000/256)

typedef __attribute__((ext_vector_type(8))) short bf16x8;
typedef __attribute__((ext_vector_type(4))) float f32x4;

__device__ __forceinline__ unsigned short f32_to_bf16(float f) {
    union { float f; uint32_t u; } c; c.f = f;
    uint32_t u = c.u;
    uint32_t r = (u + 0x7FFFu + ((u >> 16) & 1u)) >> 16;
    return (unsigned short)r;
}

__device__ __forceinline__ float bf16_to_f32(unsigned short s) {
    union { uint32_t u; float f; } c; c.u = ((uint32_t)s) << 16;
    return c.f;
}

// ---------------------------------------------------------------------------
// GEMM: h[r] = bf16( x @ W[r] )  (unchanged from round 1, verified)
// ---------------------------------------------------------------------------
__global__ __launch_bounds__(256, 2)
void gemm_xw(const float* __restrict__ x, const float* __restrict__ w,
             unsigned short* __restrict__ h)
{
    const int bm = blockIdx.x, bn = blockIdx.y, r = blockIdx.z;
    const float* __restrict__ W = w + (size_t)r * KF * NF;
    unsigned short* __restrict__ H = h + (size_t)r * M_NODES * NF;

    __shared__ short As[128 * 40];
    __shared__ short Bs[128 * 40];

    const int t = threadIdx.x;
    const int lane = t & 63;
    const int wid = t >> 6;
    const int wr = wid >> 1, wc = wid & 1;
    const int l16 = lane & 15, lg = lane >> 4;

    f32x4 acc[4][4] = {};
    const int m0 = bm * 128;

    for (int kt = 0; kt < KF / 32; ++kt) {
        __syncthreads();
#pragma unroll
        for (int i = 0; i < 4; ++i) {
            int li = (i * 256 + t) * 4;
            int row = li >> 5, col = li & 31;
            int gm = m0 + row;
            float4 v = make_float4(0.f, 0.f, 0.f, 0.f);
            if (gm < M_NODES)
                v = *(const float4*)(x + (size_t)gm * KF + kt * 32 + col);
            short4 b;
            b.x = (short)f32_to_bf16(v.x);
            b.y = (short)f32_to_bf16(v.y);
            b.z = (short)f32_to_bf16(v.z);
            b.w = (short)f32_to_bf16(v.w);
            *(short4*)&As[row * 40 + col] = b;
        }
#pragma unroll
        for (int i = 0; i < 8; ++i) {
            int p = i * 256 + t;
            int n = p & 127, kp = p >> 7;
            float v0 = W[(size_t)(kt * 32 + kp * 2 + 0) * NF + bn * 128 + n];
            float v1 = W[(size_t)(kt * 32 + kp * 2 + 1) * NF + bn * 128 + n];
            uint32_t pk = (uint32_t)f32_to_bf16(v0) | ((uint32_t)f32_to_bf16(v1) << 16);
            *(uint32_t*)&Bs[n * 40 + kp * 2] = pk;
        }
        __syncthreads();

        bf16x8 a[4], b[4];
#pragma unroll
        for (int i = 0; i < 4; ++i)
            a[i] = *(bf16x8*)&As[(wr * 64 + i * 16 + l16) * 40 + lg * 8];
#pragma unroll
        for (int j = 0; j < 4; ++j)
            b[j] = *(bf16x8*)&Bs[(wc * 64 + j * 16 + l16) * 40 + lg * 8];
#pragma unroll
        for (int i = 0; i < 4; ++i)
#pragma unroll
            for (int j = 0; j < 4; ++j)
                acc[i][j] = __builtin_amdgcn_mfma_f32_16x16x32_bf16(
                    a[i], b[j], acc[i][j], 0, 0, 0);
    }

#pragma unroll
    for (int i = 0; i < 4; ++i) {
        int row_base = m0 + wr * 64 + i * 16 + lg * 4;
#pragma unroll
        for (int q = 0; q < 4; ++q) {
            int row = row_base + q;
            if (row < M_NODES) {
#pragma unroll
                for (int j = 0; j < 4; ++j) {
                    int col = bn * 128 + wc * 64 + j * 16 + l16;
                    H[(size_t)row * NF + col] = f32_to_bf16(acc[i][j][q]);
                }
            }
        }
    }
}

// ---------------------------------------------------------------------------
// Counting-sort CSR build (keyed by dst, merged across relations)
// ---------------------------------------------------------------------------
__global__ __launch_bounds__(256)
void k_hist(const int* __restrict__ dst, int* __restrict__ counts)
{
    int e = blockIdx.x * 256 + threadIdx.x;
    if (e < TOT_EDGES) atomicAdd(&counts[dst[e]], 1);
}

// per-block sums of counts
__global__ __launch_bounds__(256)
void k_blocksum(const int* __restrict__ counts, int* __restrict__ bsum)
{
    __shared__ int s[256];
    int i = blockIdx.x * 256 + threadIdx.x;
    s[threadIdx.x] = (i < M_NODES) ? counts[i] : 0;
    __syncthreads();
    for (int st = 128; st > 0; st >>= 1) {
        if (threadIdx.x < st) s[threadIdx.x] += s[threadIdx.x + st];
        __syncthreads();
    }
    if (threadIdx.x == 0) bsum[blockIdx.x] = s[0];
}

// serial exclusive scan of NB block sums (NB=391, trivial)
__global__ void k_scanbsum(const int* __restrict__ bsum, int* __restrict__ bpre)
{
    if (threadIdx.x == 0 && blockIdx.x == 0) {
        int acc = 0;
        for (int i = 0; i < NB; ++i) { bpre[i] = acc; acc += bsum[i]; }
    }
}

// per-block exclusive scan -> global offsets; also init scatter cursors
__global__ __launch_bounds__(256)
void k_offsets(const int* __restrict__ counts, const int* __restrict__ bpre,
               int* __restrict__ off, int* __restrict__ cur)
{
    __shared__ int s[257];
    int i = blockIdx.x * 256 + threadIdx.x;
    int v = (i < M_NODES) ? counts[i] : 0;
    if (threadIdx.x == 0) {
        // serial scan of 256 elems by one thread; blocks provide parallelism
        s[0] = 0;
    }
    s[threadIdx.x + 1] = v;   // staged raw values at +1
    __syncthreads();
    if (threadIdx.x == 0) {
        int acc = 0;
        for (int j = 0; j < 256; ++j) { int t = s[j + 1]; s[j + 1] = acc; acc += t; }
    }
    __syncthreads();
    if (i < M_NODES) {
        int o = bpre[blockIdx.x] + s[threadIdx.x + 1];
        off[i] = o;
        cur[i] = o;
    }
}

// scatter edge -> perm[pos] = h row index (r*M + src)
__global__ __launch_bounds__(256)
void k_scatter(const int* __restrict__ src, const int* __restrict__ dst,
               int* __restrict__ cur, int* __restrict__ perm)
{
    int e = blockIdx.x * 256 + threadIdx.x;
    if (e >= TOT_EDGES) return;
    int d = dst[e];
    int r = e / NEDGES;
    int pos = atomicAdd(&cur[d], 1);
    perm[pos] = r * M_NODES + src[e];
}

// ---------------------------------------------------------------------------
// Gather-sum + ReLU: one wave per destination node. No atomics.
// ---------------------------------------------------------------------------
__global__ __launch_bounds__(256)
void k_agg(const unsigned short* __restrict__ h,
           const int* __restrict__ off, const int* __restrict__ counts,
           const int* __restrict__ perm, float* __restrict__ out)
{
    int w = (blockIdx.x * 256 + threadIdx.x) >> 6;   // dst node
    if (w >= M_NODES) return;
    int lane = threadIdx.x & 63;
    int start = off[w];
    int n = counts[w];

    float acc0 = 0.f, acc1 = 0.f, acc2 = 0.f, acc3 = 0.f;
    for (int j = 0; j < n; ++j) {
        int hrow = perm[start + j];                  // wave-uniform broadcast load
        ushort4 v = *(const ushort4*)(h + (size_t)hrow * NF + lane * 4);
        acc0 += bf16_to_f32(v.x);
        acc1 += bf16_to_f32(v.y);
        acc2 += bf16_to_f32(v.z);
        acc3 += bf16_to_f32(v.w);
    }
    float4 o;
    o.x = fmaxf(acc0, 0.f);
    o.y = fmaxf(acc1, 0.f);
    o.z = fmaxf(acc2, 0.f);
    o.w = fmaxf(acc3, 0.f);
    *(float4*)(out + (size_t)w * NF + lane * 4) = o;
}

extern "C" void kernel_launch(void* const* d_in, const int* in_sizes, int n_in,
                              void* d_out, int out_size, void* d_ws, size_t ws_size,
                              hipStream_t stream)
{
    const float* x   = (const float*)d_in[0];
    const float* w   = (const float*)d_in[1];
    const int*   src = (const int*)d_in[2];
    const int*   dst = (const int*)d_in[3];
    float* out = (float*)d_out;

    // workspace layout
    char* ws = (char*)d_ws;
    unsigned short* h = (unsigned short*)ws;                 // 153,600,000 B
    size_t o = (size_t)NRELS * M_NODES * NF * sizeof(unsigned short);
    int* counts = (int*)(ws + o);  o += (size_t)M_NODES * 4; // 400,000
    int* off    = (int*)(ws + o);  o += (size_t)M_NODES * 4;
    int* cur    = (int*)(ws + o);  o += (size_t)M_NODES * 4;
    int* bsum   = (int*)(ws + o);  o += 2048;
    int* bpre   = (int*)(ws + o);  o += 2048;
    int* perm   = (int*)(ws + o);  o += (size_t)TOT_EDGES * 4;

    // CSR build (independent of GEMM; stream-serialized anyway)
    hipMemsetAsync(counts, 0, (size_t)M_NODES * 4, stream);

    dim3 gg((M_NODES + 127) / 128, NF / 128, NRELS);
    gemm_xw<<<gg, 256, 0, stream>>>(x, w, h);

    int eb = (TOT_EDGES + 255) / 256;
    k_hist<<<eb, 256, 0, stream>>>(dst, counts);
    k_blocksum<<<NB, 256, 0, stream>>>(counts, bsum);
    k_scanbsum<<<1, 64, 0, stream>>>(bsum, bpre);
    k_offsets<<<NB, 256, 0, stream>>>(counts, bpre, off, cur);
    k_scatter<<<eb, 256, 0, stream>>>(src, dst, cur, perm);

    int ab = (M_NODES * 64 + 255) / 256;   // one wave per node
    k_agg<<<ab, 256, 0, stream>>>(h, off, counts, perm, out);
}